// Round 2
// baseline (462.837 us; speedup 1.0000x reference)
//
#include <hip/hip_runtime.h>

// Leaky integrator: out[t] = BETA*out[t-1] + x[t], x: (T=2048, B=32, D=1024) f32.
// R4 = R3 with compile fix: __builtin_nontemporal_store needs a native clang
// vector type, not HIP_vector_type<float,4>. Store via ext_vector_type alias.
//  - float4 per thread (4 channels): 16 B/lane, 1 KB per wave load instruction
//  - ping-pong double-buffered load batches (va/vb): continuous bytes-in-flight
//  - nontemporal stores for out: keep L2/L3 for the warm-up re-reads
//  - numerics identical to R2 (WARM=128, same per-channel FMA order)

constexpr int   T_DIM = 2048;
constexpr int   BD    = 32 * 1024;     // 32768 scalar channels
constexpr int   BD4   = BD / 4;        // 8192 float4 channels
constexpr float BETA  = 0.95f;
constexpr int   CHUNK = 256;           // time steps per block
constexpr int   WARM  = 128;           // warm-up steps (beta^128 ~ 1.4e-3)
constexpr int   NCH   = T_DIM / CHUNK; // 8
constexpr int   BLOCK = 64;
constexpr int   G     = 8;             // load-batch depth (8 KB/wave in flight)

typedef float nt_f4 __attribute__((ext_vector_type(4)));  // native vec for NT store

__global__ __launch_bounds__(BLOCK)
void li_kernel(const float4* __restrict__ x, float4* __restrict__ out) {
    const int    c    = blockIdx.x * BLOCK + threadIdx.x;  // float4 channel
    const int    t0   = blockIdx.y * CHUNK;
    const size_t step = (size_t)G * BD4;

    float b0 = 0.0f, b1 = 0.0f, b2 = 0.0f, b3 = 0.0f;

    float4 va[G], vb[G];

#define LOADB(dst, base)                                                      \
    _Pragma("unroll")                                                         \
    for (int i = 0; i < G; ++i) (dst)[i] = (base)[(size_t)i * BD4];

#define ACCUM(src)                                                            \
    _Pragma("unroll")                                                         \
    for (int i = 0; i < G; ++i) {                                             \
        b0 = fmaf(BETA, b0, (src)[i].x);                                      \
        b1 = fmaf(BETA, b1, (src)[i].y);                                      \
        b2 = fmaf(BETA, b2, (src)[i].z);                                      \
        b3 = fmaf(BETA, b3, (src)[i].w);                                      \
    }

#define ACCST(src, pout)                                                      \
    _Pragma("unroll")                                                         \
    for (int i = 0; i < G; ++i) {                                             \
        b0 = fmaf(BETA, b0, (src)[i].x);                                      \
        b1 = fmaf(BETA, b1, (src)[i].y);                                      \
        b2 = fmaf(BETA, b2, (src)[i].z);                                      \
        b3 = fmaf(BETA, b3, (src)[i].w);                                      \
        nt_f4 _v = {b0, b1, b2, b3};                                          \
        __builtin_nontemporal_store(                                          \
            _v, reinterpret_cast<nt_f4*>((pout) + (size_t)i * BD4));          \
    }

    // ---- warm-up: read-only scan of the preceding WARM steps ----
    if (blockIdx.y > 0) {
        const float4* px = x + (size_t)(t0 - WARM) * BD4 + c;
        LOADB(va, px);
        for (int g = 0; g < WARM / G - 2; g += 2) {   // 7 iters = 14 batches
            LOADB(vb, px + step);
            ACCUM(va);
            LOADB(va, px + 2 * step);
            ACCUM(vb);
            px += 2 * step;
        }
        LOADB(vb, px + step);                          // batch 15
        ACCUM(va);                                     // batch 14
        ACCUM(vb);                                     // batch 15
    }

    // ---- main: scan CHUNK steps, store running state ----
    const float4* px = x   + (size_t)t0 * BD4 + c;
    float4*       po = out + (size_t)t0 * BD4 + c;
    LOADB(va, px);
    for (int g = 0; g < CHUNK / G - 2; g += 2) {       // 15 iters = 30 batches
        LOADB(vb, px + step);
        ACCST(va, po);
        LOADB(va, px + 2 * step);
        ACCST(vb, po + step);
        px += 2 * step;
        po += 2 * step;
    }
    LOADB(vb, px + step);                              // batch 31
    ACCST(va, po);                                     // batch 30
    ACCST(vb, po + step);                              // batch 31

#undef LOADB
#undef ACCUM
#undef ACCST
}

extern "C" void kernel_launch(void* const* d_in, const int* in_sizes, int n_in,
                              void* d_out, int out_size, void* d_ws, size_t ws_size,
                              hipStream_t stream) {
    const float4* x   = (const float4*)d_in[0];
    float4*       out = (float4*)d_out;

    dim3 block(BLOCK, 1, 1);
    dim3 grid(BD4 / BLOCK, NCH, 1);   // (128, 8) = 1024 blocks, 4 waves/CU
    li_kernel<<<grid, block, 0, stream>>>(x, out);
}